// Round 1
// baseline (214.354 us; speedup 1.0000x reference)
//
#include <hip/hip_runtime.h>
#include <math.h>

#define BB 4
#define NN 512
#define DD 256
#define HH 8
#define BND (BB*NN*DD)

constexpr int RB = 8;   // rows per block in the row-GEMM kernels

// ---------------- QKV projection: q/k/v = (mask? h:0) @ W ----------------
__global__ __launch_bounds__(256) void qkv_proj(
    const float* __restrict__ hg, const int* __restrict__ mask,
    const float* __restrict__ Wq, const float* __restrict__ Wk, const float* __restrict__ Wv,
    float* __restrict__ q, float* __restrict__ k, float* __restrict__ v)
{
    __shared__ float hsT[DD][RB];
    const int t = threadIdx.x;
    const int r0 = blockIdx.x * RB;
    #pragma unroll
    for (int rr = 0; rr < RB; ++rr) {
        float x = hg[(size_t)(r0 + rr) * DD + t];
        if (mask[r0 + rr] == 0) x = 0.f;
        hsT[t][rr] = x;
    }
    __syncthreads();
    float aq[RB], ak[RB], av[RB];
    #pragma unroll
    for (int rr = 0; rr < RB; ++rr) { aq[rr] = 0.f; ak[rr] = 0.f; av[rr] = 0.f; }
    for (int d = 0; d < DD; ++d) {
        const float wq = Wq[d*DD + t];
        const float wk = Wk[d*DD + t];
        const float wv = Wv[d*DD + t];
        const float4 h0 = *(const float4*)&hsT[d][0];
        const float4 h1 = *(const float4*)&hsT[d][4];
        const float hv[8] = {h0.x,h0.y,h0.z,h0.w,h1.x,h1.y,h1.z,h1.w};
        #pragma unroll
        for (int rr = 0; rr < RB; ++rr) {
            aq[rr] = fmaf(hv[rr], wq, aq[rr]);
            ak[rr] = fmaf(hv[rr], wk, ak[rr]);
            av[rr] = fmaf(hv[rr], wv, av[rr]);
        }
    }
    #pragma unroll
    for (int rr = 0; rr < RB; ++rr) {
        q[(size_t)(r0 + rr)*DD + t] = aq[rr];
        k[(size_t)(r0 + rr)*DD + t] = ak[rr];
        v[(size_t)(r0 + rr)*DD + t] = av[rr];
    }
}

// ---------------- fused bias-MLP + QK^T + softmax + PV ----------------
// block = (b, 4 consecutive query rows i0..i0+3), 256 threads.
// thread t owns key columns j0=t and j1=t+256.
__global__ __launch_bounds__(256) void fused_attn(
    const float* __restrict__ qg, const float* __restrict__ kg, const float* __restrict__ vg,
    const float* __restrict__ p, const int* __restrict__ side, const int* __restrict__ mask,
    const float* __restrict__ W1, const float* __restrict__ b1,
    const float* __restrict__ W2, const float* __restrict__ b2,
    float* __restrict__ ao)
{
    __shared__ float Lg[4][NN][HH];      // 64 KB: bias -> logits -> exp(attn)
    __shared__ float cw[DD][16];         // 16 KB packed weights: W1r0..3, b1, W2[0..7]
    __shared__ float qsT[DD][4];         // 4 KB, q rows pre-scaled by 1/sqrt(32)
    __shared__ float pjx[NN], pjy[NN];   // 4 KB
    __shared__ int   sj[NN];             // 2 KB
    __shared__ float km[NN];             // 2 KB key-mask addend
    __shared__ float red[32][8];         // reduction scratch
    __shared__ float mx[32];
    __shared__ float rs[32];

    const int t  = threadIdx.x;
    const int b  = blockIdx.x / (NN/4);
    const int i0 = (blockIdx.x % (NN/4)) * 4;

    // ---- stage packed weights ----
    cw[t][0] = W1[t];
    cw[t][1] = W1[DD + t];
    cw[t][2] = W1[2*DD + t];
    cw[t][3] = W1[3*DD + t];
    cw[t][4] = b1[t];
    #pragma unroll
    for (int hh = 0; hh < HH; ++hh) cw[t][5+hh] = W2[t*HH + hh];

    const float qscale = 0.17677669529663687f; // 1/sqrt(32)
    #pragma unroll
    for (int ii = 0; ii < 4; ++ii)
        qsT[t][ii] = qg[(size_t)(b*NN + i0 + ii)*DD + t] * qscale;

    for (int jj = t; jj < NN; jj += 256) {
        pjx[jj] = p[(size_t)(b*NN + jj)*2 + 0];
        pjy[jj] = p[(size_t)(b*NN + jj)*2 + 1];
        sj[jj]  = side[b*NN + jj];
        km[jj]  = (mask[b*NN + jj] != 0) ? 0.f : -1e9f;
    }

    float pix[4], piy[4]; int si[4];
    #pragma unroll
    for (int ii = 0; ii < 4; ++ii) {
        pix[ii] = p[(size_t)(b*NN + i0 + ii)*2 + 0];
        piy[ii] = p[(size_t)(b*NN + i0 + ii)*2 + 1];
        si[ii]  = side[b*NN + i0 + ii];
    }
    __syncthreads();

    const int j0 = t, j1 = t + 256;

    // pairwise features for this thread's two j columns x 4 i rows
    float fx[2][4], fy[2][4], fd[2][4], ft[2][4];
    #pragma unroll
    for (int js = 0; js < 2; ++js) {
        const int jj = js ? j1 : j0;
        const float px = pjx[jj], py = pjy[jj];
        const int ss = sj[jj];
        #pragma unroll
        for (int ii = 0; ii < 4; ++ii) {
            const float dx = pix[ii] - px;
            const float dy = piy[ii] - py;
            fx[js][ii] = dx; fy[js][ii] = dy;
            fd[js][ii] = fmaxf(sqrtf(dx*dx + dy*dy), 1e-6f);
            ft[js][ii] = (si[ii] == ss) ? 1.f : 0.f;
        }
    }

    float b2r[HH];
    #pragma unroll
    for (int hh = 0; hh < HH; ++hh) b2r[hh] = b2[hh];

    // accumulators: logits = b2 + keymask + biasMLP + q.k
    float acc[2][4][HH];
    #pragma unroll
    for (int js = 0; js < 2; ++js) {
        const float kmv = km[js ? j1 : j0];
        #pragma unroll
        for (int ii = 0; ii < 4; ++ii)
            #pragma unroll
            for (int hh = 0; hh < HH; ++hh)
                acc[js][ii][hh] = b2r[hh] + kmv;
    }

    const float* kr0 = kg + (size_t)(b*NN + j0)*DD;
    const float* kr1 = kg + (size_t)(b*NN + j1)*DD;

    // fused c-loop: bias-MLP hidden units + QK^T segment dot
    #pragma unroll
    for (int hh = 0; hh < HH; ++hh) {          // compile-time head segment
        for (int c8 = 0; c8 < 8; ++c8) {       // runtime, 4 c's per iter
            const int cb = hh*32 + c8*4;
            const float4 k0 = *(const float4*)(kr0 + cb);
            const float4 k1 = *(const float4*)(kr1 + cb);
            #pragma unroll
            for (int u = 0; u < 4; ++u) {
                const int c = cb + u;
                const float4 wA = *(const float4*)&cw[c][0];  // W1 rows 0..3
                const float4 wB = *(const float4*)&cw[c][4];  // b1, W2[0..2]
                const float4 wC = *(const float4*)&cw[c][8];  // W2[3..6]
                const float  wD = cw[c][12];                  // W2[7]
                const float4 q4 = *(const float4*)&qsT[c][0];
                #pragma unroll
                for (int js = 0; js < 2; ++js) {
                    const float kc = js ? (&k1.x)[u] : (&k0.x)[u];
                    #pragma unroll
                    for (int ii = 0; ii < 4; ++ii) {
                        float a = fmaf(fx[js][ii], wA.x,
                                  fmaf(fy[js][ii], wA.y,
                                  fmaf(fd[js][ii], wA.z,
                                  fmaf(ft[js][ii], wA.w, wB.x))));
                        a = fmaxf(a, 0.f);
                        float* A = acc[js][ii];
                        A[0] = fmaf(a, wB.y, A[0]);
                        A[1] = fmaf(a, wB.z, A[1]);
                        A[2] = fmaf(a, wB.w, A[2]);
                        A[3] = fmaf(a, wC.x, A[3]);
                        A[4] = fmaf(a, wC.y, A[4]);
                        A[5] = fmaf(a, wC.z, A[5]);
                        A[6] = fmaf(a, wC.w, A[6]);
                        A[7] = fmaf(a, wD,   A[7]);
                        A[hh] = fmaf((&q4.x)[ii], kc, A[hh]); // QK^T (q pre-scaled)
                    }
                }
            }
        }
    }

    // write logits to LDS
    #pragma unroll
    for (int js = 0; js < 2; ++js) {
        const int jj = js ? j1 : j0;
        #pragma unroll
        for (int ii = 0; ii < 4; ++ii)
            #pragma unroll
            for (int hh = 0; hh < HH; ++hh)
                Lg[ii][jj][hh] = acc[js][ii][hh];
    }
    __syncthreads();

    // ---- softmax over j for each of 32 (ii,hh) combos ----
    const int combo = t >> 3;        // 0..31
    const int sub   = t & 7;
    const int ci = combo >> 3;       // ii
    const int ch = combo & 7;        // hh
    {
        float m = -1e30f;
        for (int j = sub; j < NN; j += 8) m = fmaxf(m, Lg[ci][j][ch]);
        red[combo][sub] = m;
    }
    __syncthreads();
    if (t < 32) {
        float mm = red[t][0];
        #pragma unroll
        for (int s = 1; s < 8; ++s) mm = fmaxf(mm, red[t][s]);
        mx[t] = mm;
    }
    __syncthreads();
    {
        const float M = mx[combo];
        float s = 0.f;
        for (int j = sub; j < NN; j += 8) {
            const float e = __expf(Lg[ci][j][ch] - M);
            Lg[ci][j][ch] = e;
            s += e;
        }
        red[combo][sub] = s;
    }
    __syncthreads();
    if (t < 32) {
        float s = 0.f;
        #pragma unroll
        for (int ss = 0; ss < 8; ++ss) s += red[t][ss];
        rs[t] = 1.f / s;
    }
    __syncthreads();

    // ---- PV: thread t owns output column c = t ----
    {
        const int c = t;
        const int hh = c >> 5;
        const float* vb = vg + (size_t)b*NN*DD + c;
        float o[4] = {0.f, 0.f, 0.f, 0.f};
        for (int j = 0; j < NN; ++j) {
            const float vv = vb[(size_t)j*DD];
            #pragma unroll
            for (int ii = 0; ii < 4; ++ii)
                o[ii] = fmaf(Lg[ii][j][hh], vv, o[ii]);
        }
        #pragma unroll
        for (int ii = 0; ii < 4; ++ii)
            ao[(size_t)(b*NN + i0 + ii)*DD + c] = o[ii] * rs[ii*HH + hh];
    }
}

// ---------------- output projection: out = ao @ Wo ----------------
__global__ __launch_bounds__(256) void oproj(
    const float* __restrict__ X, const float* __restrict__ W, float* __restrict__ Y)
{
    __shared__ float xsT[DD][RB];
    const int t = threadIdx.x;
    const int r0 = blockIdx.x * RB;
    #pragma unroll
    for (int rr = 0; rr < RB; ++rr)
        xsT[t][rr] = X[(size_t)(r0 + rr)*DD + t];
    __syncthreads();
    float a[RB];
    #pragma unroll
    for (int rr = 0; rr < RB; ++rr) a[rr] = 0.f;
    for (int d = 0; d < DD; ++d) {
        const float w = W[d*DD + t];
        const float4 h0 = *(const float4*)&xsT[d][0];
        const float4 h1 = *(const float4*)&xsT[d][4];
        const float hv[8] = {h0.x,h0.y,h0.z,h0.w,h1.x,h1.y,h1.z,h1.w};
        #pragma unroll
        for (int rr = 0; rr < RB; ++rr)
            a[rr] = fmaf(hv[rr], w, a[rr]);
    }
    #pragma unroll
    for (int rr = 0; rr < RB; ++rr)
        Y[(size_t)(r0 + rr)*DD + t] = a[rr];
}

extern "C" void kernel_launch(void* const* d_in, const int* in_sizes, int n_in,
                              void* d_out, int out_size, void* d_ws, size_t ws_size,
                              hipStream_t stream) {
    const float* hg   = (const float*)d_in[0];
    const float* p    = (const float*)d_in[1];
    const int*   side = (const int*)d_in[2];
    const int*   mask = (const int*)d_in[3];
    const float* Wq   = (const float*)d_in[4];
    const float* Wk   = (const float*)d_in[5];
    const float* Wv   = (const float*)d_in[6];
    const float* Wo   = (const float*)d_in[7];
    const float* W1   = (const float*)d_in[8];
    const float* b1   = (const float*)d_in[9];
    const float* W2   = (const float*)d_in[10];
    const float* b2   = (const float*)d_in[11];

    float* ws = (float*)d_ws;
    float* q  = ws;
    float* k  = ws + BND;
    float* v  = ws + 2*BND;
    float* ao = ws + 3*BND;

    qkv_proj<<<(BB*NN)/RB, 256, 0, stream>>>(hg, mask, Wq, Wk, Wv, q, k, v);
    fused_attn<<<BB*(NN/4), 256, 0, stream>>>(q, k, v, p, side, mask, W1, b1, W2, b2, ao);
    oproj<<<(BB*NN)/RB, 256, 0, stream>>>(ao, Wo, (float*)d_out);
}

// Round 2
// 174.514 us; speedup vs baseline: 1.2283x; 1.2283x over previous
//
#include <hip/hip_runtime.h>
#include <math.h>

#define BB 4
#define NN 512
#define DD 256
#define HH 8
#define BND (BB*NN*DD)

constexpr int RB = 8;   // rows per block in the row-GEMM kernels

// ---------------- pack bias-MLP weights into [256][16] records ----------------
// layout per c: [0..3]=W1[0..3][c], [4]=b1[c], [5..12]=W2[c][0..7], [13..15]=pad
__global__ __launch_bounds__(256) void pack_weights(
    const float* __restrict__ W1, const float* __restrict__ b1,
    const float* __restrict__ W2, float* __restrict__ pw)
{
    const int c = threadIdx.x;
    float r[16];
    r[0] = W1[c];
    r[1] = W1[DD + c];
    r[2] = W1[2*DD + c];
    r[3] = W1[3*DD + c];
    r[4] = b1[c];
    #pragma unroll
    for (int hh = 0; hh < HH; ++hh) r[5+hh] = W2[c*HH + hh];
    r[13] = r[14] = r[15] = 0.f;
    #pragma unroll
    for (int u = 0; u < 16; ++u) pw[c*16 + u] = r[u];
}

// ---------------- QKV projection: q/k/v = (mask? h:0) @ W ----------------
// k is pre-scaled by 1/sqrt(DH) so fused_attn's QK dot needs no extra scale.
__global__ __launch_bounds__(256) void qkv_proj(
    const float* __restrict__ hg, const int* __restrict__ mask,
    const float* __restrict__ Wq, const float* __restrict__ Wk, const float* __restrict__ Wv,
    float* __restrict__ q, float* __restrict__ k, float* __restrict__ v)
{
    __shared__ float hsT[DD][RB];
    const int t = threadIdx.x;
    const int r0 = blockIdx.x * RB;
    #pragma unroll
    for (int rr = 0; rr < RB; ++rr) {
        float x = hg[(size_t)(r0 + rr) * DD + t];
        if (mask[r0 + rr] == 0) x = 0.f;
        hsT[t][rr] = x;
    }
    __syncthreads();
    float aq[RB], ak[RB], av[RB];
    #pragma unroll
    for (int rr = 0; rr < RB; ++rr) { aq[rr] = 0.f; ak[rr] = 0.f; av[rr] = 0.f; }
    for (int d = 0; d < DD; ++d) {
        const float wq = Wq[d*DD + t];
        const float wk = Wk[d*DD + t];
        const float wv = Wv[d*DD + t];
        const float4 h0 = *(const float4*)&hsT[d][0];
        const float4 h1 = *(const float4*)&hsT[d][4];
        const float hv[8] = {h0.x,h0.y,h0.z,h0.w,h1.x,h1.y,h1.z,h1.w};
        #pragma unroll
        for (int rr = 0; rr < RB; ++rr) {
            aq[rr] = fmaf(hv[rr], wq, aq[rr]);
            ak[rr] = fmaf(hv[rr], wk, ak[rr]);
            av[rr] = fmaf(hv[rr], wv, av[rr]);
        }
    }
    const float qscale = 0.17677669529663687f; // 1/sqrt(32)
    #pragma unroll
    for (int rr = 0; rr < RB; ++rr) {
        q[(size_t)(r0 + rr)*DD + t] = aq[rr];
        k[(size_t)(r0 + rr)*DD + t] = ak[rr] * qscale;
        v[(size_t)(r0 + rr)*DD + t] = av[rr];
    }
}

// ---------------- fused bias-MLP + QK^T + softmax + PV ----------------
// block = (b, 4 consecutive query rows i0..i0+3), 256 threads.
// thread t owns key columns j0=t and j1=t+256.
// Weights/q read at wave-uniform addresses (scalar pipe); inner loop has no LDS.
__global__ __launch_bounds__(256) void fused_attn(
    const float* __restrict__ qg, const float* __restrict__ kg, const float* __restrict__ vg,
    const float* __restrict__ p, const int* __restrict__ side, const int* __restrict__ mask,
    const float* __restrict__ pw, const float* __restrict__ b2,
    float* __restrict__ ao)
{
    // row = ii*8+hh; pad 516 (stride ≡ 4 mod 32 → conflict-free writes, ≤2-way reads)
    __shared__ float Lg[32][516];        // 66 KB: logits -> exp(attn)
    __shared__ float red[32][8];
    __shared__ float mx[32];
    __shared__ float rs[32];

    const int t  = threadIdx.x;
    const int b  = blockIdx.x / (NN/4);
    const int i0 = (blockIdx.x % (NN/4)) * 4;

    // uniform per-block query-row metadata
    float pix[4], piy[4]; int si[4];
    #pragma unroll
    for (int ii = 0; ii < 4; ++ii) {
        pix[ii] = p[(size_t)(b*NN + i0 + ii)*2 + 0];
        piy[ii] = p[(size_t)(b*NN + i0 + ii)*2 + 1];
        si[ii]  = side[b*NN + i0 + ii];
    }

    const int j0 = t, j1 = t + 256;

    // per-lane key metadata (direct global reads, no staging)
    const float pjx0 = p[(size_t)(b*NN + j0)*2 + 0];
    const float pjy0 = p[(size_t)(b*NN + j0)*2 + 1];
    const float pjx1 = p[(size_t)(b*NN + j1)*2 + 0];
    const float pjy1 = p[(size_t)(b*NN + j1)*2 + 1];
    const int   sj0  = side[b*NN + j0];
    const int   sj1  = side[b*NN + j1];
    const float km0  = (mask[b*NN + j0] != 0) ? 0.f : -1e9f;
    const float km1  = (mask[b*NN + j1] != 0) ? 0.f : -1e9f;

    // pairwise features for this thread's two j columns x 4 i rows
    float fx[2][4], fy[2][4], fd[2][4], ft[2][4];
    #pragma unroll
    for (int js = 0; js < 2; ++js) {
        const float px = js ? pjx1 : pjx0;
        const float py = js ? pjy1 : pjy0;
        const int   ss = js ? sj1  : sj0;
        #pragma unroll
        for (int ii = 0; ii < 4; ++ii) {
            const float dx = pix[ii] - px;
            const float dy = piy[ii] - py;
            fx[js][ii] = dx; fy[js][ii] = dy;
            fd[js][ii] = fmaxf(sqrtf(dx*dx + dy*dy), 1e-6f);
            ft[js][ii] = (si[ii] == ss) ? 1.f : 0.f;
        }
    }

    float b2r[HH];
    #pragma unroll
    for (int hh = 0; hh < HH; ++hh) b2r[hh] = b2[hh];

    // accumulators: logits = b2 + keymask + biasMLP + q.k
    float acc[2][4][HH];
    #pragma unroll
    for (int js = 0; js < 2; ++js) {
        const float kmv = js ? km1 : km0;
        #pragma unroll
        for (int ii = 0; ii < 4; ++ii)
            #pragma unroll
            for (int hh = 0; hh < HH; ++hh)
                acc[js][ii][hh] = b2r[hh] + kmv;
    }

    const float* kr0 = kg + (size_t)(b*NN + j0)*DD;
    const float* kr1 = kg + (size_t)(b*NN + j1)*DD;
    const float* qp0 = qg + (size_t)(b*NN + i0)*DD;
    const float* qp1 = qp0 + DD;
    const float* qp2 = qp0 + 2*DD;
    const float* qp3 = qp0 + 3*DD;

    // fused c-loop: bias-MLP hidden units + QK^T segment dot
    #pragma unroll
    for (int hh = 0; hh < HH; ++hh) {          // compile-time head segment
        for (int c8 = 0; c8 < 8; ++c8) {       // runtime, 4 c's per iter
            const int cb = hh*32 + c8*4;
            const float4 k0 = *(const float4*)(kr0 + cb);
            const float4 k1 = *(const float4*)(kr1 + cb);
            #pragma unroll
            for (int u = 0; u < 4; ++u) {
                const int c = cb + u;
                const float4 wA = *(const float4*)(pw + c*16 + 0); // W1 rows 0..3
                const float4 wB = *(const float4*)(pw + c*16 + 4); // b1, W2[0..2]
                const float4 wC = *(const float4*)(pw + c*16 + 8); // W2[3..6]
                const float  wD = pw[c*16 + 12];                   // W2[7]
                const float qv[4] = { qp0[c], qp1[c], qp2[c], qp3[c] };
                #pragma unroll
                for (int js = 0; js < 2; ++js) {
                    const float kc = js ? (&k1.x)[u] : (&k0.x)[u];
                    #pragma unroll
                    for (int ii = 0; ii < 4; ++ii) {
                        float a = fmaf(fx[js][ii], wA.x,
                                  fmaf(fy[js][ii], wA.y,
                                  fmaf(fd[js][ii], wA.z,
                                  fmaf(ft[js][ii], wA.w, wB.x))));
                        a = fmaxf(a, 0.f);
                        float* A = acc[js][ii];
                        A[0] = fmaf(a, wB.y, A[0]);
                        A[1] = fmaf(a, wB.z, A[1]);
                        A[2] = fmaf(a, wB.w, A[2]);
                        A[3] = fmaf(a, wC.x, A[3]);
                        A[4] = fmaf(a, wC.y, A[4]);
                        A[5] = fmaf(a, wC.z, A[5]);
                        A[6] = fmaf(a, wC.w, A[6]);
                        A[7] = fmaf(a, wD,   A[7]);
                        A[hh] = fmaf(qv[ii], kc, A[hh]); // QK^T (k pre-scaled)
                    }
                }
            }
        }
    }

    // write logits to LDS (row = ii*8+hh; conflict-free: bank = 4*row + t)
    #pragma unroll
    for (int js = 0; js < 2; ++js) {
        const int jj = js ? j1 : j0;
        #pragma unroll
        for (int ii = 0; ii < 4; ++ii)
            #pragma unroll
            for (int hh = 0; hh < HH; ++hh)
                Lg[ii*8 + hh][jj] = acc[js][ii][hh];
    }
    __syncthreads();

    // ---- softmax over j for each of 32 rows (ii,hh) ----
    const int combo = t >> 3;        // 0..31 = row
    const int sub   = t & 7;
    {
        float m = -1e30f;
        for (int j = sub; j < NN; j += 8) m = fmaxf(m, Lg[combo][j]);
        red[combo][sub] = m;
    }
    __syncthreads();
    if (t < 32) {
        float mm = red[t][0];
        #pragma unroll
        for (int s = 1; s < 8; ++s) mm = fmaxf(mm, red[t][s]);
        mx[t] = mm;
    }
    __syncthreads();
    {
        const float M = mx[combo];
        float s = 0.f;
        for (int j = sub; j < NN; j += 8) {
            const float e = __expf(Lg[combo][j] - M);
            Lg[combo][j] = e;
            s += e;
        }
        red[combo][sub] = s;
    }
    __syncthreads();
    if (t < 32) {
        float s = 0.f;
        #pragma unroll
        for (int ss = 0; ss < 8; ++ss) s += red[t][ss];
        rs[t] = 1.f / s;
    }
    __syncthreads();

    // ---- PV: thread t owns output column c = t ----
    {
        const int c = t;
        const int hh = c >> 5;
        const float* vb = vg + (size_t)b*NN*DD + c;
        float o[4] = {0.f, 0.f, 0.f, 0.f};
        for (int j = 0; j < NN; ++j) {
            const float vv = vb[(size_t)j*DD];
            #pragma unroll
            for (int ii = 0; ii < 4; ++ii)
                o[ii] = fmaf(Lg[ii*8 + hh][j], vv, o[ii]);
        }
        #pragma unroll
        for (int ii = 0; ii < 4; ++ii)
            ao[(size_t)(b*NN + i0 + ii)*DD + c] = o[ii] * rs[ii*8 + hh];
    }
}

// ---------------- output projection: out = ao @ Wo ----------------
__global__ __launch_bounds__(256) void oproj(
    const float* __restrict__ X, const float* __restrict__ W, float* __restrict__ Y)
{
    __shared__ float xsT[DD][RB];
    const int t = threadIdx.x;
    const int r0 = blockIdx.x * RB;
    #pragma unroll
    for (int rr = 0; rr < RB; ++rr)
        xsT[t][rr] = X[(size_t)(r0 + rr)*DD + t];
    __syncthreads();
    float a[RB];
    #pragma unroll
    for (int rr = 0; rr < RB; ++rr) a[rr] = 0.f;
    for (int d = 0; d < DD; ++d) {
        const float w = W[d*DD + t];
        const float4 h0 = *(const float4*)&xsT[d][0];
        const float4 h1 = *(const float4*)&xsT[d][4];
        const float hv[8] = {h0.x,h0.y,h0.z,h0.w,h1.x,h1.y,h1.z,h1.w};
        #pragma unroll
        for (int rr = 0; rr < RB; ++rr)
            a[rr] = fmaf(hv[rr], w, a[rr]);
    }
    #pragma unroll
    for (int rr = 0; rr < RB; ++rr)
        Y[(size_t)(r0 + rr)*DD + t] = a[rr];
}

extern "C" void kernel_launch(void* const* d_in, const int* in_sizes, int n_in,
                              void* d_out, int out_size, void* d_ws, size_t ws_size,
                              hipStream_t stream) {
    const float* hg   = (const float*)d_in[0];
    const float* p    = (const float*)d_in[1];
    const int*   side = (const int*)d_in[2];
    const int*   mask = (const int*)d_in[3];
    const float* Wq   = (const float*)d_in[4];
    const float* Wk   = (const float*)d_in[5];
    const float* Wv   = (const float*)d_in[6];
    const float* Wo   = (const float*)d_in[7];
    const float* W1   = (const float*)d_in[8];
    const float* b1   = (const float*)d_in[9];
    const float* W2   = (const float*)d_in[10];
    const float* b2   = (const float*)d_in[11];

    float* ws = (float*)d_ws;
    float* q  = ws;
    float* k  = ws + BND;
    float* v  = ws + 2*BND;
    float* ao = ws + 3*BND;
    float* pw = ws + 4*BND;   // 256*16 packed MLP weights

    pack_weights<<<1, 256, 0, stream>>>(W1, b1, W2, pw);
    qkv_proj<<<(BB*NN)/RB, 256, 0, stream>>>(hg, mask, Wq, Wk, Wv, q, k, v);
    fused_attn<<<BB*(NN/4), 256, 0, stream>>>(q, k, v, p, side, mask, pw, b2, ao);
    oproj<<<(BB*NN)/RB, 256, 0, stream>>>(ao, Wo, (float*)d_out);
}

// Round 5
// 154.073 us; speedup vs baseline: 1.3912x; 1.1327x over previous
//
#include <hip/hip_runtime.h>
#include <math.h>

#define BB 4
#define NN 512
#define DD 256
#define HH 8
#define BND (BB*NN*DD)

typedef _Float16 h2 __attribute__((ext_vector_type(2)));

static __device__ __forceinline__ h2 u2h(unsigned u) { return __builtin_bit_cast(h2, u); }
static __device__ __forceinline__ float u2f(unsigned u) { return __builtin_bit_cast(float, u); }
// RNE pack (v_cvt_f16_f32 x2 + v_pack_b32_f16) — NOT cvt_pkrtz (RTZ doubles RMS error)
static __device__ __forceinline__ h2 pk2(float a, float b) {
    h2 r; r[0] = (_Float16)a; r[1] = (_Float16)b; return r;
}
static __device__ __forceinline__ unsigned pk2u(float a, float b) {
    return __builtin_bit_cast(unsigned, pk2(a, b));
}
static __device__ __forceinline__ float dot2(h2 a, h2 b, float c) {
    return __builtin_amdgcn_fdot2(a, b, c, false);
}

constexpr int RB = 8;   // rows per block in the row-GEMM kernels

// ---------------- pack bias-MLP weights into per-c-pair records ----------------
// record cp (c0=2cp,c1=2cp+1), 16 dwords:
// [0]=(w1x,w1y)c0 f16x2  [1]=(w1d,w1t)c0  [2],[3]= same c1
// [4]=b1[c0] f32  [5]=b1[c1] f32  [6..13]=(W2[c0][h],W2[c1][h]) f16x2  [14,15]=0
__global__ __launch_bounds__(128) void pack_w2(
    const float* __restrict__ W1, const float* __restrict__ b1,
    const float* __restrict__ W2, unsigned* __restrict__ pw2)
{
    const int cp = threadIdx.x;       // 0..127
    const int c0 = 2*cp, c1 = c0 + 1;
    unsigned r[16];
    r[0] = pk2u(W1[c0],      W1[DD + c0]);
    r[1] = pk2u(W1[2*DD+c0], W1[3*DD + c0]);
    r[2] = pk2u(W1[c1],      W1[DD + c1]);
    r[3] = pk2u(W1[2*DD+c1], W1[3*DD + c1]);
    r[4] = __builtin_bit_cast(unsigned, b1[c0]);
    r[5] = __builtin_bit_cast(unsigned, b1[c1]);
    #pragma unroll
    for (int h = 0; h < HH; ++h)
        r[6+h] = pk2u(W2[c0*HH + h], W2[c1*HH + h]);
    r[14] = r[15] = 0u;
    #pragma unroll
    for (int u = 0; u < 16; ++u) pw2[cp*16 + u] = r[u];
}

// ---------------- QKV projection ----------------
// emits q16 (f16), k16 (f16, pre-scaled by 1/sqrt(32)), v (f32)
__global__ __launch_bounds__(256) void qkv_proj(
    const float* __restrict__ hg, const int* __restrict__ mask,
    const float* __restrict__ Wq, const float* __restrict__ Wk, const float* __restrict__ Wv,
    _Float16* __restrict__ q16, _Float16* __restrict__ k16, float* __restrict__ v)
{
    __shared__ float hsT[DD][RB];
    const int t = threadIdx.x;
    const int r0 = blockIdx.x * RB;
    #pragma unroll
    for (int rr = 0; rr < RB; ++rr) {
        float x = hg[(size_t)(r0 + rr) * DD + t];
        if (mask[r0 + rr] == 0) x = 0.f;
        hsT[t][rr] = x;
    }
    __syncthreads();
    float aq[RB], ak[RB], av[RB];
    #pragma unroll
    for (int rr = 0; rr < RB; ++rr) { aq[rr] = 0.f; ak[rr] = 0.f; av[rr] = 0.f; }
    for (int d = 0; d < DD; ++d) {
        const float wq = Wq[d*DD + t];
        const float wk = Wk[d*DD + t];
        const float wv = Wv[d*DD + t];
        const float4 h0 = *(const float4*)&hsT[d][0];
        const float4 h1 = *(const float4*)&hsT[d][4];
        const float hv[8] = {h0.x,h0.y,h0.z,h0.w,h1.x,h1.y,h1.z,h1.w};
        #pragma unroll
        for (int rr = 0; rr < RB; ++rr) {
            aq[rr] = fmaf(hv[rr], wq, aq[rr]);
            ak[rr] = fmaf(hv[rr], wk, ak[rr]);
            av[rr] = fmaf(hv[rr], wv, av[rr]);
        }
    }
    const float qscale = 0.17677669529663687f; // 1/sqrt(32)
    #pragma unroll
    for (int rr = 0; rr < RB; ++rr) {
        q16[(size_t)(r0 + rr)*DD + t] = (_Float16)aq[rr];
        k16[(size_t)(r0 + rr)*DD + t] = (_Float16)(ak[rr] * qscale);
        v  [(size_t)(r0 + rr)*DD + t] = av[rr];
    }
}

// ---------------- fused bias-MLP + QK^T + softmax + PV ----------------
// block = (b, 4 query rows), 256 threads; thread t owns key cols t and t+256.
// MLP first+second layer and QK all via v_dot2_f32_f16 (2 MAC/instr).
__global__ __launch_bounds__(256) void fused_attn(
    const unsigned* __restrict__ q16u, const unsigned* __restrict__ k16u,
    const float* __restrict__ vg,
    const float* __restrict__ p, const int* __restrict__ side, const int* __restrict__ mask,
    const unsigned* __restrict__ pw2, const float* __restrict__ b2,
    float* __restrict__ ao)
{
    __shared__ float Lg[32][516];        // 66 KB: logits -> exp(attn)
    __shared__ float red[32][8];
    __shared__ float mx[32];
    __shared__ float rs[32];

    const int t  = threadIdx.x;
    const int b  = blockIdx.x / (NN/4);
    const int i0 = (blockIdx.x % (NN/4)) * 4;

    float pix[4], piy[4]; int si[4];
    #pragma unroll
    for (int ii = 0; ii < 4; ++ii) {
        pix[ii] = p[(size_t)(b*NN + i0 + ii)*2 + 0];
        piy[ii] = p[(size_t)(b*NN + i0 + ii)*2 + 1];
        si[ii]  = side[b*NN + i0 + ii];
    }

    const int j0 = t, j1 = t + 256;
    const float pjx0 = p[(size_t)(b*NN + j0)*2 + 0];
    const float pjy0 = p[(size_t)(b*NN + j0)*2 + 1];
    const float pjx1 = p[(size_t)(b*NN + j1)*2 + 0];
    const float pjy1 = p[(size_t)(b*NN + j1)*2 + 1];
    const int   sj0  = side[b*NN + j0];
    const int   sj1  = side[b*NN + j1];
    const float km0  = (mask[b*NN + j0] != 0) ? 0.f : -1e9f;
    const float km1  = (mask[b*NN + j1] != 0) ? 0.f : -1e9f;

    // packed pairwise features: (dx,dy) and (dist,team) as f16x2 (RNE)
    h2 fxy[2][4], fdt[2][4];
    #pragma unroll
    for (int js = 0; js < 2; ++js) {
        const float px = js ? pjx1 : pjx0;
        const float py = js ? pjy1 : pjy0;
        const int   ss = js ? sj1  : sj0;
        #pragma unroll
        for (int ii = 0; ii < 4; ++ii) {
            const float dx = pix[ii] - px;
            const float dy = piy[ii] - py;
            const float di = fmaxf(sqrtf(dx*dx + dy*dy), 1e-6f);
            const float tm = (si[ii] == ss) ? 1.f : 0.f;
            fxy[js][ii] = pk2(dx, dy);
            fdt[js][ii] = pk2(di, tm);
        }
    }

    float b2r[HH];
    #pragma unroll
    for (int hh = 0; hh < HH; ++hh) b2r[hh] = b2[hh];

    float acc[2][4][HH];
    #pragma unroll
    for (int js = 0; js < 2; ++js) {
        const float kmv = js ? km1 : km0;
        #pragma unroll
        for (int ii = 0; ii < 4; ++ii)
            #pragma unroll
            for (int hh = 0; hh < HH; ++hh)
                acc[js][ii][hh] = b2r[hh] + kmv;
    }

    const unsigned* kr0 = k16u + (size_t)(b*NN + j0)*(DD/2);
    const unsigned* kr1 = k16u + (size_t)(b*NN + j1)*(DD/2);
    const unsigned* qu  = q16u + (size_t)(b*NN + i0)*(DD/2);

    // c-pair loop: 128 pairs; head hh covers cp in [hh*16, hh*16+16)
    #pragma unroll
    for (int hh = 0; hh < HH; ++hh) {
        for (int g = 0; g < 4; ++g) {
            const int cp0 = hh*16 + g*4;
            const uint4 ka = *(const uint4*)(kr0 + cp0);
            const uint4 kb = *(const uint4*)(kr1 + cp0);
            #pragma unroll
            for (int u = 0; u < 4; ++u) {
                const int cp = cp0 + u;
                const unsigned* rec = pw2 + cp*16;
                const h2 wxy0 = u2h(rec[0]);
                const h2 wdt0 = u2h(rec[1]);
                const h2 wxy1 = u2h(rec[2]);
                const h2 wdt1 = u2h(rec[3]);
                const float b10 = u2f(rec[4]);
                const float b11 = u2f(rec[5]);
                h2 w2p[HH];
                #pragma unroll
                for (int h = 0; h < HH; ++h) w2p[h] = u2h(rec[6+h]);
                h2 qp[4];
                #pragma unroll
                for (int ii = 0; ii < 4; ++ii) qp[ii] = u2h(qu[ii*(DD/2) + cp]);
                #pragma unroll
                for (int js = 0; js < 2; ++js) {
                    const h2 kp = u2h(js ? (&kb.x)[u] : (&ka.x)[u]);
                    #pragma unroll
                    for (int ii = 0; ii < 4; ++ii) {
                        const float a0 = dot2(fxy[js][ii], wxy0, dot2(fdt[js][ii], wdt0, b10));
                        const float a1 = dot2(fxy[js][ii], wxy1, dot2(fdt[js][ii], wdt1, b11));
                        const h2 ap = pk2(fmaxf(a0, 0.f), fmaxf(a1, 0.f));
                        float* A = acc[js][ii];
                        #pragma unroll
                        for (int h = 0; h < HH; ++h) A[h] = dot2(ap, w2p[h], A[h]);
                        A[hh] = dot2(qp[ii], kp, A[hh]);   // QK^T (k pre-scaled)
                    }
                }
            }
        }
    }

    // write logits to LDS (row = ii*8+hh; conflict-free)
    #pragma unroll
    for (int js = 0; js < 2; ++js) {
        const int jj = js ? j1 : j0;
        #pragma unroll
        for (int ii = 0; ii < 4; ++ii)
            #pragma unroll
            for (int hh = 0; hh < HH; ++hh)
                Lg[ii*8 + hh][jj] = acc[js][ii][hh];
    }
    __syncthreads();

    // ---- softmax over j for each of 32 rows (ii,hh) ----
    const int combo = t >> 3;
    const int sub   = t & 7;
    {
        float m = -1e30f;
        for (int j = sub; j < NN; j += 8) m = fmaxf(m, Lg[combo][j]);
        red[combo][sub] = m;
    }
    __syncthreads();
    if (t < 32) {
        float mm = red[t][0];
        #pragma unroll
        for (int s = 1; s < 8; ++s) mm = fmaxf(mm, red[t][s]);
        mx[t] = mm;
    }
    __syncthreads();
    {
        const float M = mx[combo];
        float s = 0.f;
        for (int j = sub; j < NN; j += 8) {
            const float e = __expf(Lg[combo][j] - M);
            Lg[combo][j] = e;
            s += e;
        }
        red[combo][sub] = s;
    }
    __syncthreads();
    if (t < 32) {
        float s = 0.f;
        #pragma unroll
        for (int ss = 0; ss < 8; ++ss) s += red[t][ss];
        rs[t] = 1.f / s;
    }
    __syncthreads();

    // ---- PV: thread t owns output column c = t ----
    {
        const int c = t;
        const int hh = c >> 5;
        const float* vb = vg + (size_t)b*NN*DD + c;
        float o[4] = {0.f, 0.f, 0.f, 0.f};
        for (int j = 0; j < NN; ++j) {
            const float vv = vb[(size_t)j*DD];
            #pragma unroll
            for (int ii = 0; ii < 4; ++ii)
                o[ii] = fmaf(Lg[ii*8 + hh][j], vv, o[ii]);
        }
        #pragma unroll
        for (int ii = 0; ii < 4; ++ii)
            ao[(size_t)(b*NN + i0 + ii)*DD + c] = o[ii] * rs[ii*8 + hh];
    }
}

// ---------------- output projection: out = ao @ Wo ----------------
__global__ __launch_bounds__(256) void oproj(
    const float* __restrict__ X, const float* __restrict__ W, float* __restrict__ Y)
{
    __shared__ float xsT[DD][RB];
    const int t = threadIdx.x;
    const int r0 = blockIdx.x * RB;
    #pragma unroll
    for (int rr = 0; rr < RB; ++rr)
        xsT[t][rr] = X[(size_t)(r0 + rr)*DD + t];
    __syncthreads();
    float a[RB];
    #pragma unroll
    for (int rr = 0; rr < RB; ++rr) a[rr] = 0.f;
    for (int d = 0; d < DD; ++d) {
        const float w = W[d*DD + t];
        const float4 h0 = *(const float4*)&xsT[d][0];
        const float4 h1 = *(const float4*)&xsT[d][4];
        const float hv[8] = {h0.x,h0.y,h0.z,h0.w,h1.x,h1.y,h1.z,h1.w};
        #pragma unroll
        for (int rr = 0; rr < RB; ++rr)
            a[rr] = fmaf(hv[rr], w, a[rr]);
    }
    #pragma unroll
    for (int rr = 0; rr < RB; ++rr)
        Y[(size_t)(r0 + rr)*DD + t] = a[rr];
}

extern "C" void kernel_launch(void* const* d_in, const int* in_sizes, int n_in,
                              void* d_out, int out_size, void* d_ws, size_t ws_size,
                              hipStream_t stream) {
    const float* hg   = (const float*)d_in[0];
    const float* p    = (const float*)d_in[1];
    const int*   side = (const int*)d_in[2];
    const int*   mask = (const int*)d_in[3];
    const float* Wq   = (const float*)d_in[4];
    const float* Wk   = (const float*)d_in[5];
    const float* Wv   = (const float*)d_in[6];
    const float* Wo   = (const float*)d_in[7];
    const float* W1   = (const float*)d_in[8];
    const float* b1   = (const float*)d_in[9];
    const float* W2   = (const float*)d_in[10];
    const float* b2   = (const float*)d_in[11];

    float* ws = (float*)d_ws;
    float* v  = ws;                                   // BND f32
    float* ao = ws + BND;                             // BND f32
    _Float16* q16 = (_Float16*)(ws + 2*BND);          // BND f16
    _Float16* k16 = q16 + BND;                        // BND f16
    unsigned* pw2 = (unsigned*)(k16 + BND);           // 128*16 u32

    pack_w2<<<1, 128, 0, stream>>>(W1, b1, W2, pw2);
    qkv_proj<<<(BB*NN)/RB, 256, 0, stream>>>(hg, mask, Wq, Wk, Wv, q16, k16, v);
    fused_attn<<<BB*(NN/4), 256, 0, stream>>>((const unsigned*)q16, (const unsigned*)k16,
                                              v, p, side, mask, pw2, b2, ao);
    oproj<<<(BB*NN)/RB, 256, 0, stream>>>(ao, Wo, (float*)d_out);
}

// Round 6
// 127.358 us; speedup vs baseline: 1.6831x; 1.2098x over previous
//
#include <hip/hip_runtime.h>
#include <math.h>

#define BB 4
#define NN 512
#define DD 256
#define HH 8
#define BND (BB*NN*DD)

typedef _Float16 h2 __attribute__((ext_vector_type(2)));

static __device__ __forceinline__ h2 u2h(unsigned u) { return __builtin_bit_cast(h2, u); }
static __device__ __forceinline__ float u2f(unsigned u) { return __builtin_bit_cast(float, u); }
// RNE pack (v_cvt_f16_f32 x2 + v_pack_b32_f16) — NOT cvt_pkrtz (RTZ doubles RMS error)
static __device__ __forceinline__ h2 pk2(float a, float b) {
    h2 r; r[0] = (_Float16)a; r[1] = (_Float16)b; return r;
}
static __device__ __forceinline__ unsigned pk2u(float a, float b) {
    return __builtin_bit_cast(unsigned, pk2(a, b));
}
static __device__ __forceinline__ float dot2(h2 a, h2 b, float c) {
    return __builtin_amdgcn_fdot2(a, b, c, false);
}

constexpr int RB = 8;   // rows per block in the row-GEMM kernels

// ---------------- pack bias-MLP weights into per-c-pair records ----------------
// record cp (c0=2cp,c1=2cp+1), 16 dwords:
// [0]=(w1x,w1y)c0 f16x2  [1]=(w1d,w1t)c0  [2],[3]= same c1
// [4]=b1[c0] f32  [5]=b1[c1] f32  [6..13]=(W2[c0][h],W2[c1][h]) f16x2  [14,15]=0
__global__ __launch_bounds__(128) void pack_w2(
    const float* __restrict__ W1, const float* __restrict__ b1,
    const float* __restrict__ W2, unsigned* __restrict__ pw2)
{
    const int cp = threadIdx.x;       // 0..127
    const int c0 = 2*cp, c1 = c0 + 1;
    unsigned r[16];
    r[0] = pk2u(W1[c0],      W1[DD + c0]);
    r[1] = pk2u(W1[2*DD+c0], W1[3*DD + c0]);
    r[2] = pk2u(W1[c1],      W1[DD + c1]);
    r[3] = pk2u(W1[2*DD+c1], W1[3*DD + c1]);
    r[4] = __builtin_bit_cast(unsigned, b1[c0]);
    r[5] = __builtin_bit_cast(unsigned, b1[c1]);
    #pragma unroll
    for (int h = 0; h < HH; ++h)
        r[6+h] = pk2u(W2[c0*HH + h], W2[c1*HH + h]);
    r[14] = r[15] = 0u;
    #pragma unroll
    for (int u = 0; u < 16; ++u) pw2[cp*16 + u] = r[u];
}

// ---------------- QKV projection ----------------
// emits q16 (f16), k16 (f16, pre-scaled by 1/sqrt(32)), v16 packed [j/2][c] pairs
__global__ __launch_bounds__(256) void qkv_proj(
    const float* __restrict__ hg, const int* __restrict__ mask,
    const float* __restrict__ Wq, const float* __restrict__ Wk, const float* __restrict__ Wv,
    _Float16* __restrict__ q16, _Float16* __restrict__ k16, _Float16* __restrict__ v16h)
{
    __shared__ float hsT[DD][RB];
    const int t = threadIdx.x;
    const int r0 = blockIdx.x * RB;
    #pragma unroll
    for (int rr = 0; rr < RB; ++rr) {
        float x = hg[(size_t)(r0 + rr) * DD + t];
        if (mask[r0 + rr] == 0) x = 0.f;
        hsT[t][rr] = x;
    }
    __syncthreads();
    float aq[RB], ak[RB], av[RB];
    #pragma unroll
    for (int rr = 0; rr < RB; ++rr) { aq[rr] = 0.f; ak[rr] = 0.f; av[rr] = 0.f; }
    for (int d = 0; d < DD; ++d) {
        const float wq = Wq[d*DD + t];
        const float wk = Wk[d*DD + t];
        const float wv = Wv[d*DD + t];
        const float4 h0 = *(const float4*)&hsT[d][0];
        const float4 h1 = *(const float4*)&hsT[d][4];
        const float hv[8] = {h0.x,h0.y,h0.z,h0.w,h1.x,h1.y,h1.z,h1.w};
        #pragma unroll
        for (int rr = 0; rr < RB; ++rr) {
            aq[rr] = fmaf(hv[rr], wq, aq[rr]);
            ak[rr] = fmaf(hv[rr], wk, ak[rr]);
            av[rr] = fmaf(hv[rr], wv, av[rr]);
        }
    }
    const float qscale = 0.17677669529663687f; // 1/sqrt(32)
    #pragma unroll
    for (int rr = 0; rr < RB; ++rr) {
        const int r = r0 + rr;
        q16[(size_t)r*DD + t] = (_Float16)aq[rr];
        k16[(size_t)r*DD + t] = (_Float16)(ak[rr] * qscale);
        // packed-pair layout: dword (r>>1)*DD + t holds (v[2m][c], v[2m+1][c])
        v16h[((size_t)(r >> 1)*DD + t)*2 + (r & 1)] = (_Float16)av[rr];
    }
}

// ---------------- fused bias-MLP + QK^T + softmax + PV ----------------
// block = (b, 4 query rows), 256 threads; thread t owns adjacent key cols 2t, 2t+1.
// Logits/attn stored packed-f16 in LDS (33 KB) -> 4 blocks/CU.
__global__ __launch_bounds__(256, 4) void fused_attn(
    const unsigned* __restrict__ q16u, const unsigned* __restrict__ k16u,
    const unsigned* __restrict__ v16p,
    const float* __restrict__ p, const int* __restrict__ side, const int* __restrict__ mask,
    const unsigned* __restrict__ pw2, const float* __restrict__ b2,
    float* __restrict__ ao)
{
    __shared__ unsigned Lgh[32][260];    // 33 KB packed f16 pairs: logits -> exp
    __shared__ float red[32][8];
    __shared__ float mx[32];
    __shared__ float rs[32];

    const int t  = threadIdx.x;
    const int b  = blockIdx.x / (NN/4);
    const int i0 = (blockIdx.x % (NN/4)) * 4;

    float pix[4], piy[4]; int si[4];
    #pragma unroll
    for (int ii = 0; ii < 4; ++ii) {
        pix[ii] = p[(size_t)(b*NN + i0 + ii)*2 + 0];
        piy[ii] = p[(size_t)(b*NN + i0 + ii)*2 + 1];
        si[ii]  = side[b*NN + i0 + ii];
    }

    const int j0 = 2*t, j1 = 2*t + 1;
    const float pjx0 = p[(size_t)(b*NN + j0)*2 + 0];
    const float pjy0 = p[(size_t)(b*NN + j0)*2 + 1];
    const float pjx1 = p[(size_t)(b*NN + j1)*2 + 0];
    const float pjy1 = p[(size_t)(b*NN + j1)*2 + 1];
    const int   sj0  = side[b*NN + j0];
    const int   sj1  = side[b*NN + j1];
    // -3e4 (f16-representable) instead of -1e9: same softmax result
    const float km0  = (mask[b*NN + j0] != 0) ? 0.f : -3.0e4f;
    const float km1  = (mask[b*NN + j1] != 0) ? 0.f : -3.0e4f;

    // packed pairwise features: (dx,dy) and (dist,team) as f16x2 (RNE)
    h2 fxy[2][4], fdt[2][4];
    #pragma unroll
    for (int js = 0; js < 2; ++js) {
        const float px = js ? pjx1 : pjx0;
        const float py = js ? pjy1 : pjy0;
        const int   ss = js ? sj1  : sj0;
        #pragma unroll
        for (int ii = 0; ii < 4; ++ii) {
            const float dx = pix[ii] - px;
            const float dy = piy[ii] - py;
            const float di = fmaxf(sqrtf(dx*dx + dy*dy), 1e-6f);
            const float tm = (si[ii] == ss) ? 1.f : 0.f;
            fxy[js][ii] = pk2(dx, dy);
            fdt[js][ii] = pk2(di, tm);
        }
    }

    float b2r[HH];
    #pragma unroll
    for (int hh = 0; hh < HH; ++hh) b2r[hh] = b2[hh];

    float acc[2][4][HH];
    #pragma unroll
    for (int js = 0; js < 2; ++js) {
        const float kmv = js ? km1 : km0;
        #pragma unroll
        for (int ii = 0; ii < 4; ++ii)
            #pragma unroll
            for (int hh = 0; hh < HH; ++hh)
                acc[js][ii][hh] = b2r[hh] + kmv;
    }

    const unsigned* kr0 = k16u + (size_t)(b*NN + j0)*(DD/2);
    const unsigned* kr1 = kr0 + (DD/2);
    const unsigned* qu  = q16u + (size_t)(b*NN + i0)*(DD/2);

    // c-pair loop: 128 pairs; head hh covers cp in [hh*16, hh*16+16)
    #pragma unroll
    for (int hh = 0; hh < HH; ++hh) {
        for (int g = 0; g < 4; ++g) {
            const int cp0 = hh*16 + g*4;
            const uint4 ka = *(const uint4*)(kr0 + cp0);
            const uint4 kb = *(const uint4*)(kr1 + cp0);
            #pragma unroll
            for (int u = 0; u < 4; ++u) {
                const int cp = cp0 + u;
                const unsigned* rec = pw2 + cp*16;
                const h2 wxy0 = u2h(rec[0]);
                const h2 wdt0 = u2h(rec[1]);
                const h2 wxy1 = u2h(rec[2]);
                const h2 wdt1 = u2h(rec[3]);
                const float b10 = u2f(rec[4]);
                const float b11 = u2f(rec[5]);
                h2 w2p[HH];
                #pragma unroll
                for (int h = 0; h < HH; ++h) w2p[h] = u2h(rec[6+h]);
                h2 qp[4];
                #pragma unroll
                for (int ii = 0; ii < 4; ++ii) qp[ii] = u2h(qu[ii*(DD/2) + cp]);
                #pragma unroll
                for (int js = 0; js < 2; ++js) {
                    const h2 kp = u2h(js ? (&kb.x)[u] : (&ka.x)[u]);
                    #pragma unroll
                    for (int ii = 0; ii < 4; ++ii) {
                        const float a0 = dot2(fxy[js][ii], wxy0, dot2(fdt[js][ii], wdt0, b10));
                        const float a1 = dot2(fxy[js][ii], wxy1, dot2(fdt[js][ii], wdt1, b11));
                        // pack then packed-relu (rounding commutes with relu)
                        h2 ap = pk2(a0, a1);
                        ap = __builtin_elementwise_max(ap, h2{(_Float16)0.f, (_Float16)0.f});
                        float* A = acc[js][ii];
                        #pragma unroll
                        for (int h = 0; h < HH; ++h) A[h] = dot2(ap, w2p[h], A[h]);
                        A[hh] = dot2(qp[ii], kp, A[hh]);   // QK^T (k pre-scaled)
                    }
                }
            }
        }
    }

    // write packed logits to LDS (row = ii*8+hh, col = t) — conflict-free
    #pragma unroll
    for (int ii = 0; ii < 4; ++ii)
        #pragma unroll
        for (int hh = 0; hh < HH; ++hh)
            Lgh[ii*8 + hh][t] = pk2u(acc[0][ii][hh], acc[1][ii][hh]);
    __syncthreads();

    // ---- softmax over j for each of 32 rows (ii,hh); 8 threads per row ----
    const int combo = t >> 3;
    const int sub   = t & 7;
    {
        h2 pm = u2h(0xFC00FC00u);  // (-inf, -inf)
        for (int jp = sub; jp < NN/2; jp += 8)
            pm = __builtin_elementwise_max(pm, u2h(Lgh[combo][jp]));
        red[combo][sub] = fmaxf((float)pm[0], (float)pm[1]);
    }
    __syncthreads();
    if (t < 32) {
        float mm = red[t][0];
        #pragma unroll
        for (int s = 1; s < 8; ++s) mm = fmaxf(mm, red[t][s]);
        mx[t] = mm;
    }
    __syncthreads();
    {
        const float M = mx[combo];
        float s = 0.f;
        for (int jp = sub; jp < NN/2; jp += 8) {
            const h2 l = u2h(Lgh[combo][jp]);
            const float e0 = __expf((float)l[0] - M);
            const float e1 = __expf((float)l[1] - M);
            s += e0 + e1;
            Lgh[combo][jp] = pk2u(e0, e1);
        }
        red[combo][sub] = s;
    }
    __syncthreads();
    if (t < 32) {
        float s = 0.f;
        #pragma unroll
        for (int ss = 0; ss < 8; ++ss) s += red[t][ss];
        rs[t] = 1.f / s;
    }
    __syncthreads();

    // ---- PV: thread t owns output column c = t; dot2 over packed j-pairs ----
    {
        const int c = t;
        const int hh = c >> 5;
        const unsigned* vb = v16p + (size_t)b*(NN/2)*DD + c;
        float o[4] = {0.f, 0.f, 0.f, 0.f};
        for (int jp = 0; jp < NN/2; ++jp) {
            const h2 vp = u2h(vb[(size_t)jp*DD]);
            #pragma unroll
            for (int ii = 0; ii < 4; ++ii)
                o[ii] = dot2(u2h(Lgh[ii*8 + hh][jp]), vp, o[ii]);
        }
        #pragma unroll
        for (int ii = 0; ii < 4; ++ii)
            ao[(size_t)(b*NN + i0 + ii)*DD + c] = o[ii] * rs[ii*8 + hh];
    }
}

// ---------------- output projection: out = ao @ Wo ----------------
__global__ __launch_bounds__(256) void oproj(
    const float* __restrict__ X, const float* __restrict__ W, float* __restrict__ Y)
{
    __shared__ float xsT[DD][RB];
    const int t = threadIdx.x;
    const int r0 = blockIdx.x * RB;
    #pragma unroll
    for (int rr = 0; rr < RB; ++rr)
        xsT[t][rr] = X[(size_t)(r0 + rr)*DD + t];
    __syncthreads();
    float a[RB];
    #pragma unroll
    for (int rr = 0; rr < RB; ++rr) a[rr] = 0.f;
    for (int d = 0; d < DD; ++d) {
        const float w = W[d*DD + t];
        const float4 h0 = *(const float4*)&xsT[d][0];
        const float4 h1 = *(const float4*)&xsT[d][4];
        const float hv[8] = {h0.x,h0.y,h0.z,h0.w,h1.x,h1.y,h1.z,h1.w};
        #pragma unroll
        for (int rr = 0; rr < RB; ++rr)
            a[rr] = fmaf(hv[rr], w, a[rr]);
    }
    #pragma unroll
    for (int rr = 0; rr < RB; ++rr)
        Y[(size_t)(r0 + rr)*DD + t] = a[rr];
}

extern "C" void kernel_launch(void* const* d_in, const int* in_sizes, int n_in,
                              void* d_out, int out_size, void* d_ws, size_t ws_size,
                              hipStream_t stream) {
    const float* hg   = (const float*)d_in[0];
    const float* p    = (const float*)d_in[1];
    const int*   side = (const int*)d_in[2];
    const int*   mask = (const int*)d_in[3];
    const float* Wq   = (const float*)d_in[4];
    const float* Wk   = (const float*)d_in[5];
    const float* Wv   = (const float*)d_in[6];
    const float* Wo   = (const float*)d_in[7];
    const float* W1   = (const float*)d_in[8];
    const float* b1   = (const float*)d_in[9];
    const float* W2   = (const float*)d_in[10];
    const float* b2   = (const float*)d_in[11];

    float* ws = (float*)d_ws;
    float* ao = ws;                                   // BND f32
    _Float16* q16 = (_Float16*)(ws + BND);            // BND f16
    _Float16* k16 = q16 + BND;                        // BND f16
    _Float16* v16 = k16 + BND;                        // BND f16 (packed pairs)
    unsigned* pw2 = (unsigned*)(v16 + BND);           // 128*16 u32

    pack_w2<<<1, 128, 0, stream>>>(W1, b1, W2, pw2);
    qkv_proj<<<(BB*NN)/RB, 256, 0, stream>>>(hg, mask, Wq, Wk, Wv, q16, k16, v16);
    fused_attn<<<BB*(NN/4), 256, 0, stream>>>((const unsigned*)q16, (const unsigned*)k16,
                                              (const unsigned*)v16, p, side, mask, pw2, b2, ao);
    oproj<<<(BB*NN)/RB, 256, 0, stream>>>(ao, Wo, (float*)d_out);
}